// Round 2
// baseline (298.396 us; speedup 1.0000x reference)
//
#include <hip/hip_runtime.h>
#include <math.h>

// Problem constants (from reference)
constexpr int B_ = 256;
constexpr int S_ = 512;
constexpr int D_ = 256;
constexpr int A_ = 128;   // ATT
constexpr int BS = B_ * S_;   // 131072 rows

// ---------------- K1: scores[b*S+s] = exp( tanh(x_row @ W + b) . u ) ----------
// Block: 256 threads. Tile: 64 rows x 128 att cols. Register tile 8x4/thread.
constexpr int ROWS = 64;
constexpr int DK   = 32;   // d-chunk staged per iteration
constexpr int XP   = 68;   // padded row length of transposed x tile

__global__ __launch_bounds__(256) void k_scores(
    const float* __restrict__ x, const float* __restrict__ W,
    const float* __restrict__ bvec, const float* __restrict__ u,
    float* __restrict__ scores)
{
    __shared__ float xT[DK][XP];     // transposed x tile: xT[d][row]
    __shared__ float Ws[DK][A_];     // W tile: Ws[d][att]

    const int t   = threadIdx.x;
    const int row0 = blockIdx.x * ROWS;
    const int tr  = t >> 5;          // 0..7  -> owns rows tr*8 .. tr*8+7
    const int tc  = t & 31;          // 0..31 -> owns cols tc*4 .. tc*4+3

    float acc[8][4];
#pragma unroll
    for (int i = 0; i < 8; ++i)
#pragma unroll
        for (int j = 0; j < 4; ++j) acc[i][j] = 0.f;

    for (int dk0 = 0; dk0 < D_; dk0 += DK) {
        __syncthreads();   // protect LDS reused from previous chunk
        // stage x tile (64 rows x 32 d), transposed into xT. 512 float4 total, 2/thread.
#pragma unroll
        for (int i = 0; i < 2; ++i) {
            int idx = t + 256 * i;
            int r  = idx >> 3;      // row within tile (8 float4 per row-chunk)
            int dq = idx & 7;       // which float4 of the 32-d chunk
            float4 v = *(const float4*)(x + (size_t)(row0 + r) * D_ + dk0 + dq * 4);
            xT[dq * 4 + 0][r] = v.x;
            xT[dq * 4 + 1][r] = v.y;
            xT[dq * 4 + 2][r] = v.z;
            xT[dq * 4 + 3][r] = v.w;
        }
        // stage W tile: rows dk0..dk0+31 of W are contiguous (32*128 floats)
        {
            const float4* src = (const float4*)(W + dk0 * A_);
            float4* dst = (float4*)&Ws[0][0];
#pragma unroll
            for (int i = 0; i < 4; ++i)
                dst[t + 256 * i] = src[t + 256 * i];
        }
        __syncthreads();

#pragma unroll 8
        for (int dk = 0; dk < DK; ++dk) {
            float xr[8], wr[4];
            *(float4*)&xr[0] = *(const float4*)&xT[dk][tr * 8];     // broadcast reads
            *(float4*)&xr[4] = *(const float4*)&xT[dk][tr * 8 + 4];
            *(float4*)&wr[0] = *(const float4*)&Ws[dk][tc * 4];     // contiguous reads
#pragma unroll
            for (int i = 0; i < 8; ++i)
#pragma unroll
                for (int j = 0; j < 4; ++j)
                    acc[i][j] = fmaf(xr[i], wr[j], acc[i][j]);
        }
    }

    // epilogue: + bias, tanh, dot with u over this thread's 4 cols
    float4 bv = *(const float4*)(bvec + tc * 4);
    float4 uv = *(const float4*)(u + tc * 4);
    float part[8];
#pragma unroll
    for (int i = 0; i < 8; ++i) {
        float s = tanhf(acc[i][0] + bv.x) * uv.x;
        s      += tanhf(acc[i][1] + bv.y) * uv.y;
        s      += tanhf(acc[i][2] + bv.z) * uv.z;
        s      += tanhf(acc[i][3] + bv.w) * uv.w;
        part[i] = s;
    }
    // reduce across the 32 lanes owning the cols (lanes [0,32) and [32,64) of a
    // wave are independent groups; xor masks <32 stay within each group)
#pragma unroll
    for (int m = 16; m >= 1; m >>= 1)
#pragma unroll
        for (int i = 0; i < 8; ++i)
            part[i] += __shfl_xor(part[i], m, 64);

    if (tc == 0) {
#pragma unroll
        for (int i = 0; i < 8; ++i)
            scores[row0 + tr * 8 + i] = expf(part[i]);   // faithful: no max-subtraction
    }
}

// ---------------- K2: out[b,d] = sum_s x[b,s,d] * score[b,s] / (sum_s score + 1e-8) ---
__global__ __launch_bounds__(512) void k_out(
    const float* __restrict__ x, const float* __restrict__ scores,
    float* __restrict__ out)
{
    __shared__ float sc[S_];
    __shared__ float red[8];
    __shared__ float pbuf[D_];

    const int t = threadIdx.x;      // 0..511
    const int b = blockIdx.x;       // 0..255

    float v = scores[(size_t)b * S_ + t];
    sc[t] = v;
    // block-wide sum of 512 scores
#pragma unroll
    for (int m = 32; m >= 1; m >>= 1) v += __shfl_xor(v, m, 64);
    if ((t & 63) == 0) red[t >> 6] = v;
    __syncthreads();
    float denom = 0.f;
#pragma unroll
    for (int i = 0; i < 8; ++i) denom += red[i];
    const float inv = 1.0f / (denom + 1e-8f);

    const int d  = t & 255;
    const int sh = t >> 8;          // 0 or 1: which half of the seq
    const float* xp = x + (size_t)b * S_ * D_ + (size_t)sh * 256 * D_ + d;
    const float* scp = &sc[sh * 256];

    float a0 = 0.f, a1 = 0.f, a2 = 0.f, a3 = 0.f;
#pragma unroll 4
    for (int k = 0; k < 256; k += 4) {
        a0 = fmaf(xp[(size_t)(k + 0) * D_], scp[k + 0], a0);
        a1 = fmaf(xp[(size_t)(k + 1) * D_], scp[k + 1], a1);
        a2 = fmaf(xp[(size_t)(k + 2) * D_], scp[k + 2], a2);
        a3 = fmaf(xp[(size_t)(k + 3) * D_], scp[k + 3], a3);
    }
    float accv = (a0 + a1) + (a2 + a3);
    if (sh == 1) pbuf[d] = accv;
    __syncthreads();
    if (sh == 0) out[b * D_ + d] = (accv + pbuf[d]) * inv;
}

extern "C" void kernel_launch(void* const* d_in, const int* in_sizes, int n_in,
                              void* d_out, int out_size, void* d_ws, size_t ws_size,
                              hipStream_t stream)
{
    const float* x    = (const float*)d_in[0];
    const float* W    = (const float*)d_in[1];
    const float* bvec = (const float*)d_in[2];
    const float* u    = (const float*)d_in[3];
    float* out    = (float*)d_out;
    float* scores = (float*)d_ws;   // BS floats = 512 KB of scratch

    k_scores<<<BS / ROWS, 256, 0, stream>>>(x, W, bvec, u, scores);
    k_out<<<B_, 512, 0, stream>>>(x, scores, out);
}

// Round 3
// 253.041 us; speedup vs baseline: 1.1792x; 1.1792x over previous
//
#include <hip/hip_runtime.h>
#include <math.h>

typedef _Float16 f16x8 __attribute__((ext_vector_type(8)));
typedef float    f32x4 __attribute__((ext_vector_type(4)));

constexpr int B_ = 256, S_ = 512, D_ = 256, A_ = 128;
constexpr int BS = B_ * S_;            // 131072 rows

// d_ws layout: [scores: BS floats][W_hi packed: 32768 f16][W_lo packed: 32768 f16]
constexpr size_t WH_OFF = (size_t)BS * sizeof(float);          // 512 KB
constexpr size_t WL_OFF = WH_OFF + (size_t)D_ * A_ * 2;        // +64 KB

// ---- K0: pack W into MFMA B-fragment order, split into f16 hi + lo ----------
// Fragment layout for mfma_f32_16x16x32_f16 (B operand): lane l supplies
// B[k = ks*32 + (l>>4)*8 + i][n = nf*16 + (l&15)], i=0..7 contiguous per lane.
// Packed index: (((ks*8 + nf)*64 + l)*8 + i)
__global__ __launch_bounds__(256) void k_packW(const float* __restrict__ W,
                                               _Float16* __restrict__ Wh,
                                               _Float16* __restrict__ Wl)
{
    int tid = blockIdx.x * 256 + threadIdx.x;   // 0..4095  (8 ks * 8 nf * 64 lanes)
    int l  = tid & 63;
    int nf = (tid >> 6) & 7;
    int ks = tid >> 9;                          // 0..7
    int n  = nf * 16 + (l & 15);
    int k0 = ks * 32 + ((l >> 4) & 3) * 8;
    f16x8 hi, lo;
#pragma unroll
    for (int i = 0; i < 8; ++i) {
        float v = W[(k0 + i) * A_ + n];
        _Float16 h = (_Float16)v;
        hi[i] = h;
        lo[i] = (_Float16)(v - (float)h);
    }
    *(f16x8*)(Wh + (size_t)tid * 8) = hi;
    *(f16x8*)(Wl + (size_t)tid * 8) = lo;
}

// ---- K1: scores = exp( tanh(x @ W + b) . u ) via 3-term split-f16 MFMA ------
// Block: 256 thr = 4 waves; wave tile = 64 rows x 128 att (4 m-frags x 8 n-frags).
// Grid 512 blocks = 2 blocks/CU. x A-frags loaded straight from global (row-major
// matches fragment layout), converted to f16 hi/lo inline. No LDS at all.
__global__ __launch_bounds__(256, 2) void k_scores(
    const float* __restrict__ x, const _Float16* __restrict__ Wh,
    const _Float16* __restrict__ Wl, const float* __restrict__ bvec,
    const float* __restrict__ u, float* __restrict__ scores)
{
    const int lane = threadIdx.x & 63;
    const int wv   = threadIdx.x >> 6;                 // 0..3
    const int row_base = blockIdx.x * 256 + wv * 64;
    const int lr = lane & 15;                          // A row / B col within frag
    const int lg = lane >> 4;                          // k-group 0..3

    const f32x4 vzero = {0.f, 0.f, 0.f, 0.f};
    f32x4 acc[4][8];
#pragma unroll
    for (int mf = 0; mf < 4; ++mf)
#pragma unroll
        for (int nf = 0; nf < 8; ++nf) acc[mf][nf] = vzero;

    for (int ks = 0; ks < 8; ++ks) {
        // A fragments: 4 m-frags, each lane reads 8 consecutive fp32 of its row
        f16x8 ah[4], al[4];
#pragma unroll
        for (int mf = 0; mf < 4; ++mf) {
            const float* xp = x + (size_t)(row_base + mf * 16 + lr) * D_ + ks * 32 + lg * 8;
            float4 v0 = *(const float4*)xp;
            float4 v1 = *(const float4*)(xp + 4);
            f16x8 h, lo;
            h[0] = (_Float16)v0.x; h[1] = (_Float16)v0.y;
            h[2] = (_Float16)v0.z; h[3] = (_Float16)v0.w;
            h[4] = (_Float16)v1.x; h[5] = (_Float16)v1.y;
            h[6] = (_Float16)v1.z; h[7] = (_Float16)v1.w;
            lo[0] = (_Float16)(v0.x - (float)h[0]); lo[1] = (_Float16)(v0.y - (float)h[1]);
            lo[2] = (_Float16)(v0.z - (float)h[2]); lo[3] = (_Float16)(v0.w - (float)h[3]);
            lo[4] = (_Float16)(v1.x - (float)h[4]); lo[5] = (_Float16)(v1.y - (float)h[5]);
            lo[6] = (_Float16)(v1.z - (float)h[6]); lo[7] = (_Float16)(v1.w - (float)h[7]);
            ah[mf] = h; al[mf] = lo;
        }
        // B fragments from packed W (L2-resident, broadcast across blocks)
        const f16x8* WhB = (const f16x8*)Wh + (size_t)ks * 8 * 64 + lane;
        const f16x8* WlB = (const f16x8*)Wl + (size_t)ks * 8 * 64 + lane;
#pragma unroll
        for (int nf = 0; nf < 8; ++nf) {
            f16x8 bh = WhB[nf * 64];
            f16x8 bl = WlB[nf * 64];
#pragma unroll
            for (int mf = 0; mf < 4; ++mf) {
                acc[mf][nf] = __builtin_amdgcn_mfma_f32_16x16x32_f16(ah[mf], bh, acc[mf][nf], 0, 0, 0);
                acc[mf][nf] = __builtin_amdgcn_mfma_f32_16x16x32_f16(ah[mf], bl, acc[mf][nf], 0, 0, 0);
                acc[mf][nf] = __builtin_amdgcn_mfma_f32_16x16x32_f16(al[mf], bh, acc[mf][nf], 0, 0, 0);
            }
        }
    }

    // Epilogue. D layout: col = nf*16 + lr, row = mf*16 + lg*4 + r.
    float bb[8], uu[8];
#pragma unroll
    for (int nf = 0; nf < 8; ++nf) {
        bb[nf] = bvec[nf * 16 + lr];
        uu[nf] = u[nf * 16 + lr];
    }
#pragma unroll
    for (int mf = 0; mf < 4; ++mf) {
#pragma unroll
        for (int r = 0; r < 4; ++r) {
            float s = 0.f;
#pragma unroll
            for (int nf = 0; nf < 8; ++nf)
                s += tanhf(acc[mf][nf][r] + bb[nf]) * uu[nf];
            // reduce over the 16 cols (lanes lr=0..15 within each 16-lane group)
#pragma unroll
            for (int m = 8; m >= 1; m >>= 1)
                s += __shfl_xor(s, m, 64);
            if (lr == 0)
                scores[row_base + mf * 16 + lg * 4 + r] = expf(s);  // faithful: no max-sub
        }
    }
}

// ---- K2: out[b,d] = sum_s x[b,s,d]*score[b,s] / (sum_s score + 1e-8) --------
// One block (512 thr = 8 waves) per b. Wave w covers s in [w*64, w*64+64),
// float4 loads over d (16B/lane, 1KB/wave/s). LDS combine across waves.
__global__ __launch_bounds__(512) void k_out(
    const float* __restrict__ x, const float* __restrict__ scores,
    float* __restrict__ out)
{
    __shared__ float sc[S_];
    __shared__ float red[8];
    __shared__ float pbuf[8][D_];

    const int t = threadIdx.x, b = blockIdx.x;
    const int lane = t & 63, w = t >> 6;

    float v = scores[(size_t)b * S_ + t];
    sc[t] = v;
    float rv = v;
#pragma unroll
    for (int m = 32; m >= 1; m >>= 1) rv += __shfl_xor(rv, m, 64);
    if (lane == 0) red[w] = rv;
    __syncthreads();

    const float* xp = x + ((size_t)b * S_ + (size_t)w * 64) * D_ + lane * 4;
    float4 a0 = {0.f, 0.f, 0.f, 0.f}, a1 = {0.f, 0.f, 0.f, 0.f};
#pragma unroll 8
    for (int j = 0; j < 64; j += 2) {
        float4 xa = *(const float4*)(xp + (size_t)j * D_);
        float4 xb = *(const float4*)(xp + (size_t)(j + 1) * D_);
        float s0 = sc[w * 64 + j], s1 = sc[w * 64 + j + 1];
        a0.x = fmaf(xa.x, s0, a0.x); a0.y = fmaf(xa.y, s0, a0.y);
        a0.z = fmaf(xa.z, s0, a0.z); a0.w = fmaf(xa.w, s0, a0.w);
        a1.x = fmaf(xb.x, s1, a1.x); a1.y = fmaf(xb.y, s1, a1.y);
        a1.z = fmaf(xb.z, s1, a1.z); a1.w = fmaf(xb.w, s1, a1.w);
    }
    float4 asum = {a0.x + a1.x, a0.y + a1.y, a0.z + a1.z, a0.w + a1.w};
    *(float4*)(&pbuf[w][lane * 4]) = asum;
    __syncthreads();

    if (t < D_) {
        float denom = 0.f;
#pragma unroll
        for (int i = 0; i < 8; ++i) denom += red[i];
        const float inv = 1.0f / (denom + 1e-8f);
        float r = 0.f;
#pragma unroll
        for (int w2 = 0; w2 < 8; ++w2) r += pbuf[w2][t];
        out[b * D_ + t] = r * inv;
    }
}

extern "C" void kernel_launch(void* const* d_in, const int* in_sizes, int n_in,
                              void* d_out, int out_size, void* d_ws, size_t ws_size,
                              hipStream_t stream)
{
    const float* x    = (const float*)d_in[0];
    const float* W    = (const float*)d_in[1];
    const float* bvec = (const float*)d_in[2];
    const float* u    = (const float*)d_in[3];
    float* out = (float*)d_out;

    float*    scores = (float*)d_ws;
    _Float16* Wh     = (_Float16*)((char*)d_ws + WH_OFF);
    _Float16* Wl     = (_Float16*)((char*)d_ws + WL_OFF);

    k_packW <<<16, 256, 0, stream>>>(W, Wh, Wl);
    k_scores<<<BS / 256, 256, 0, stream>>>(x, Wh, Wl, bvec, u, scores);
    k_out   <<<B_, 512, 0, stream>>>(x, scores, out);
}

// Round 4
// 226.147 us; speedup vs baseline: 1.3195x; 1.1189x over previous
//
#include <hip/hip_runtime.h>
#include <math.h>

typedef _Float16 f16x8 __attribute__((ext_vector_type(8)));
typedef float    f32x4 __attribute__((ext_vector_type(4)));

constexpr int B_ = 256, S_ = 512, D_ = 256, A_ = 128;
constexpr int BS = B_ * S_;            // 131072 rows

// d_ws layout: [scores: BS floats][W_hi packed: 32768 f16][W_lo packed: 32768 f16]
constexpr size_t WH_OFF = (size_t)BS * sizeof(float);          // 512 KB
constexpr size_t WL_OFF = WH_OFF + (size_t)D_ * A_ * 2;        // +64 KB

__device__ __forceinline__ float tanh_fast(float v) {
    // tanh(v) = 1 - 2/(1 + e^{2v}); handles +-inf correctly. ~2e-6 abs err.
    return 1.0f - 2.0f / (1.0f + __expf(2.0f * v));
}

// ---- K0: pack W into MFMA B-fragment order, split into f16 hi + lo ----------
// B-frag layout for mfma_f32_16x16x32_f16: lane l supplies
// B[k = ks*32 + (l>>4)*8 + i][n = nf*16 + (l&15)], i=0..7.
// Packed index: (((ks*8 + nf)*64 + l)*8 + i)    [verified: round-3 passed]
__global__ __launch_bounds__(256) void k_packW(const float* __restrict__ W,
                                               _Float16* __restrict__ Wh,
                                               _Float16* __restrict__ Wl)
{
    int tid = blockIdx.x * 256 + threadIdx.x;   // 0..4095
    int l  = tid & 63;
    int nf = (tid >> 6) & 7;
    int ks = tid >> 9;
    int n  = nf * 16 + (l & 15);
    int k0 = ks * 32 + ((l >> 4) & 3) * 8;
    f16x8 hi, lo;
#pragma unroll
    for (int i = 0; i < 8; ++i) {
        float v = W[(k0 + i) * A_ + n];
        _Float16 h = (_Float16)v;
        hi[i] = h;
        lo[i] = (_Float16)(v - (float)h);
    }
    *(f16x8*)(Wh + (size_t)tid * 8) = hi;
    *(f16x8*)(Wl + (size_t)tid * 8) = lo;
}

// ---- K1: scores = exp( tanh(x @ W + b) . u ), W-in-registers, x via LDS -----
// 512 blocks x 256 thr (4 waves). Block: 256 rows, processed as 8 tiles x 32 rows.
// Wave w owns att cols [32w, 32w+32) -> B-frags fully register-resident.
// x tile staged in LDS in fragment-major order (contiguous ds_read_b128).
__global__ __launch_bounds__(256, 2) void k_scores(
    const float* __restrict__ x, const _Float16* __restrict__ Wh,
    const _Float16* __restrict__ Wl, const float* __restrict__ bvec,
    const float* __restrict__ u, float* __restrict__ scores)
{
    __shared__ _Float16 xh[16 * 64 * 8];   // 16 frags (2 mt x 8 ks) x 64 lanes x 8 f16 = 16 KB
    __shared__ _Float16 xl[16 * 64 * 8];   // 16 KB
    __shared__ float    part[2][4][32];    // 1 KB  (parity-double-buffered partials)

    const int t    = threadIdx.x;
    const int lane = t & 63, wv = t >> 6;
    const int lr   = lane & 15, lg = lane >> 4;
    const int brow0 = blockIdx.x * 256;

    // --- B fragments: wave wv owns nf = 2wv, 2wv+1; 8 ks; hi+lo = 32 f16x8 ---
    f16x8 Bh[8][2], Bl[8][2];
#pragma unroll
    for (int ks = 0; ks < 8; ++ks)
#pragma unroll
        for (int j = 0; j < 2; ++j) {
            int nf = wv * 2 + j;
            Bh[ks][j] = *(const f16x8*)(Wh + ((size_t)(ks * 8 + nf) * 64 + lane) * 8);
            Bl[ks][j] = *(const f16x8*)(Wl + ((size_t)(ks * 8 + nf) * 64 + lane) * 8);
        }

    const float bb0 = bvec[(wv * 2 + 0) * 16 + lr], uu0 = u[(wv * 2 + 0) * 16 + lr];
    const float bb1 = bvec[(wv * 2 + 1) * 16 + lr], uu1 = u[(wv * 2 + 1) * 16 + lr];

    // staging regs: this thread stages frags f = wv*4 + it (it=0..3), 2 float4 each
    float4 ld[4][2];

    // prologue: load + stage tile 0
#pragma unroll
    for (int it = 0; it < 4; ++it) {
        int f = wv * 4 + it;
        const float* p = x + (size_t)(brow0 + ((f >> 3) << 4) + lr) * D_
                           + ((f & 7) << 5) + (lg << 3);
        ld[it][0] = *(const float4*)p;
        ld[it][1] = *(const float4*)(p + 4);
    }
#pragma unroll
    for (int it = 0; it < 4; ++it) {
        int f = wv * 4 + it;
        float v[8] = {ld[it][0].x, ld[it][0].y, ld[it][0].z, ld[it][0].w,
                      ld[it][1].x, ld[it][1].y, ld[it][1].z, ld[it][1].w};
        f16x8 hi, lo;
#pragma unroll
        for (int i = 0; i < 8; ++i) {
            _Float16 h = (_Float16)v[i];
            hi[i] = h; lo[i] = (_Float16)(v[i] - (float)h);
        }
        *(f16x8*)&xh[((size_t)f * 64 + lane) * 8] = hi;
        *(f16x8*)&xl[((size_t)f * 64 + lane) * 8] = lo;
    }

    for (int tt = 0; tt < 8; ++tt) {
        __syncthreads();                        // B1: x tile tt visible in LDS
        // combine + store scores for tile tt-1 (partials written before B1)
        if (tt > 0 && t < 32) {
            int pp = (tt - 1) & 1;
            float ss = part[pp][0][t] + part[pp][1][t] + part[pp][2][t] + part[pp][3][t];
            scores[brow0 + (tt - 1) * 32 + t] = __expf(ss);   // faithful: no max-sub
        }
        // issue global loads for tile tt+1 (latency hides under compute)
        if (tt < 7) {
#pragma unroll
            for (int it = 0; it < 4; ++it) {
                int f = wv * 4 + it;
                const float* p = x + (size_t)(brow0 + (tt + 1) * 32 + ((f >> 3) << 4) + lr) * D_
                                   + ((f & 7) << 5) + (lg << 3);
                ld[it][0] = *(const float4*)p;
                ld[it][1] = *(const float4*)(p + 4);
            }
        }
        // compute tile tt: pure ds_read + MFMA against register B
        f32x4 acc[2][2];
#pragma unroll
        for (int mt = 0; mt < 2; ++mt)
#pragma unroll
            for (int j = 0; j < 2; ++j) acc[mt][j] = (f32x4){0.f, 0.f, 0.f, 0.f};
#pragma unroll
        for (int mt = 0; mt < 2; ++mt)
#pragma unroll
            for (int ks = 0; ks < 8; ++ks) {
                int fi = mt * 8 + ks;
                f16x8 ah = *(const f16x8*)&xh[((size_t)fi * 64 + lane) * 8];
                f16x8 al = *(const f16x8*)&xl[((size_t)fi * 64 + lane) * 8];
                acc[mt][0] = __builtin_amdgcn_mfma_f32_16x16x32_f16(ah, Bh[ks][0], acc[mt][0], 0, 0, 0);
                acc[mt][0] = __builtin_amdgcn_mfma_f32_16x16x32_f16(ah, Bl[ks][0], acc[mt][0], 0, 0, 0);
                acc[mt][0] = __builtin_amdgcn_mfma_f32_16x16x32_f16(al, Bh[ks][0], acc[mt][0], 0, 0, 0);
                acc[mt][1] = __builtin_amdgcn_mfma_f32_16x16x32_f16(ah, Bh[ks][1], acc[mt][1], 0, 0, 0);
                acc[mt][1] = __builtin_amdgcn_mfma_f32_16x16x32_f16(ah, Bl[ks][1], acc[mt][1], 0, 0, 0);
                acc[mt][1] = __builtin_amdgcn_mfma_f32_16x16x32_f16(al, Bh[ks][1], acc[mt][1], 0, 0, 0);
            }
        // epilogue: tanh, dot-u partial over this wave's 32 cols, 16-lane reduce
        const int par = tt & 1;
#pragma unroll
        for (int mt = 0; mt < 2; ++mt)
#pragma unroll
            for (int r = 0; r < 4; ++r) {
                float s = tanh_fast(acc[mt][0][r] + bb0) * uu0
                        + tanh_fast(acc[mt][1][r] + bb1) * uu1;
                s += __shfl_xor(s, 8, 64);
                s += __shfl_xor(s, 4, 64);
                s += __shfl_xor(s, 2, 64);
                s += __shfl_xor(s, 1, 64);
                if (lr == 0) part[par][wv][mt * 16 + lg * 4 + r] = s;
            }
        __syncthreads();                        // B2: all reads of tile tt done
        // stage tile tt+1 into LDS (cvt + ds_write)
        if (tt < 7) {
#pragma unroll
            for (int it = 0; it < 4; ++it) {
                int f = wv * 4 + it;
                float v[8] = {ld[it][0].x, ld[it][0].y, ld[it][0].z, ld[it][0].w,
                              ld[it][1].x, ld[it][1].y, ld[it][1].z, ld[it][1].w};
                f16x8 hi, lo;
#pragma unroll
                for (int i = 0; i < 8; ++i) {
                    _Float16 h = (_Float16)v[i];
                    hi[i] = h; lo[i] = (_Float16)(v[i] - (float)h);
                }
                *(f16x8*)&xh[((size_t)f * 64 + lane) * 8] = hi;
                *(f16x8*)&xl[((size_t)f * 64 + lane) * 8] = lo;
            }
        }
    }
    __syncthreads();
    if (t < 32) {
        float ss = part[1][0][t] + part[1][1][t] + part[1][2][t] + part[1][3][t];
        scores[brow0 + 7 * 32 + t] = __expf(ss);
    }
}

// ---- K2: out[b,d] = sum_s x[b,s,d]*score[b,s] / (sum_s score + 1e-8) --------
// One block (1024 thr = 16 waves) per b; wave w covers s in [w*32, w*32+32).
// 32 independent float4 loads per lane -> deep VMEM queue, latency hidden.
__global__ __launch_bounds__(1024) void k_out(
    const float* __restrict__ x, const float* __restrict__ scores,
    float* __restrict__ out)
{
    __shared__ float sc[S_];
    __shared__ float red[8];
    __shared__ float pbuf[16][D_];

    const int t = threadIdx.x, b = blockIdx.x;
    const int lane = t & 63, w = t >> 6;

    if (t < S_) {
        float v = scores[(size_t)b * S_ + t];
        sc[t] = v;
#pragma unroll
        for (int m = 32; m >= 1; m >>= 1) v += __shfl_xor(v, m, 64);
        if (lane == 0) red[w] = v;
    }
    __syncthreads();

    const float* xp = x + ((size_t)b * S_ + (size_t)w * 32) * D_ + lane * 4;
    f32x4 a = {0.f, 0.f, 0.f, 0.f};
#pragma unroll 8
    for (int j = 0; j < 32; ++j) {
        float4 xv = *(const float4*)(xp + (size_t)j * D_);
        float s = sc[w * 32 + j];
        a[0] = fmaf(xv.x, s, a[0]);
        a[1] = fmaf(xv.y, s, a[1]);
        a[2] = fmaf(xv.z, s, a[2]);
        a[3] = fmaf(xv.w, s, a[3]);
    }
    *(f32x4*)&pbuf[w][lane * 4] = a;
    __syncthreads();

    if (t < D_) {
        float denom = 0.f;
#pragma unroll
        for (int i = 0; i < 8; ++i) denom += red[i];
        const float inv = 1.0f / (denom + 1e-8f);
        float r = 0.f;
#pragma unroll
        for (int i = 0; i < 16; ++i) r += pbuf[i][t];
        out[b * D_ + t] = r * inv;
    }
}

extern "C" void kernel_launch(void* const* d_in, const int* in_sizes, int n_in,
                              void* d_out, int out_size, void* d_ws, size_t ws_size,
                              hipStream_t stream)
{
    const float* x    = (const float*)d_in[0];
    const float* W    = (const float*)d_in[1];
    const float* bvec = (const float*)d_in[2];
    const float* u    = (const float*)d_in[3];
    float* out = (float*)d_out;

    float*    scores = (float*)d_ws;
    _Float16* Wh     = (_Float16*)((char*)d_ws + WH_OFF);
    _Float16* Wl     = (_Float16*)((char*)d_ws + WL_OFF);

    k_packW <<<16, 256, 0, stream>>>(W, Wh, Wl);
    k_scores<<<512, 256, 0, stream>>>(x, Wh, Wl, bvec, u, scores);
    k_out   <<<B_, 1024, 0, stream>>>(x, scores, out);
}

// Round 5
// 224.481 us; speedup vs baseline: 1.3293x; 1.0074x over previous
//
#include <hip/hip_runtime.h>
#include <math.h>

typedef _Float16 f16x8 __attribute__((ext_vector_type(8)));
typedef float    f32x4 __attribute__((ext_vector_type(4)));

constexpr int B_ = 256, S_ = 512, D_ = 256, A_ = 128;
constexpr int BS = B_ * S_;            // 131072 rows

__device__ __forceinline__ float tanh_fast(float v) {
    // tanh(v) = 1 - 2/(1 + e^{2v}); correct at +-inf. ~2e-6 abs err.
    return 1.0f - 2.0f / (1.0f + __expf(2.0f * v));
}

// ---- K1: scores = exp( tanh(x @ W + b) . u ), 8 waves, 1 nf-slice per wave --
// 512 blocks x 512 thr (8 waves). Block: 256 rows = 8 tiles x 32 rows.
// Wave w owns att cols [16w, 16w+16) -> B-frags (hi+lo, 8 ks) = 64 VGPR.
// W self-packed from global (no pack kernel). x staged in LDS fragment-major
// (hi/lo f16), ds_read_b128 conflict-free. T14: issue-early / write-late.
__global__ __launch_bounds__(512, 4) void k_scores(
    const float* __restrict__ x, const float* __restrict__ W,
    const float* __restrict__ bvec, const float* __restrict__ u,
    float* __restrict__ scores)
{
    __shared__ _Float16 xh[16 * 64 * 8];   // 16 frags (2 mt x 8 ks) x 64 lanes x 8 = 16 KB
    __shared__ _Float16 xl[16 * 64 * 8];   // 16 KB
    __shared__ float    part[2][8][32];    // 2 KB parity-buffered row partials

    const int t    = threadIdx.x;
    const int lane = t & 63, wv = t >> 6;        // wv = 0..7 (= nf)
    const int lr   = lane & 15, lg = lane >> 4;  // frag row/col , k-group
    const int brow0 = blockIdx.x * 256;

    // --- self-pack B fragments for nf = wv (hi + lo), straight from W -------
    // B[k = ks*32 + lg*8 + i][n = wv*16 + lr]
    f16x8 Bh[8], Bl[8];
#pragma unroll
    for (int ks = 0; ks < 8; ++ks) {
        const float* wp = W + (size_t)(ks * 32 + lg * 8) * A_ + wv * 16 + lr;
#pragma unroll
        for (int i = 0; i < 8; ++i) {
            float v = wp[(size_t)i * A_];
            _Float16 h = (_Float16)v;
            Bh[ks][i] = h;
            Bl[ks][i] = (_Float16)(v - (float)h);
        }
    }
    const float bb = bvec[wv * 16 + lr];
    const float uu = u[wv * 16 + lr];

    // staging: wave wv stages frags {2wv, 2wv+1}; frag f=(mt,ks): mt=f>>3, ks=f&7
    float4 ld[2][2];

#define K1_ISSUE(TT)                                                              \
    {                                                                             \
        _Pragma("unroll")                                                         \
        for (int ff = 0; ff < 2; ++ff) {                                          \
            int f = wv * 2 + ff;                                                  \
            const float* p = x + (size_t)(brow0 + (TT) * 32 + ((f >> 3) << 4) + lr) * D_ \
                               + ((f & 7) << 5) + (lg << 3);                      \
            ld[ff][0] = *(const float4*)p;                                        \
            ld[ff][1] = *(const float4*)(p + 4);                                  \
        }                                                                         \
    }

#define K1_STAGE()                                                                \
    {                                                                             \
        _Pragma("unroll")                                                         \
        for (int ff = 0; ff < 2; ++ff) {                                          \
            int f = wv * 2 + ff;                                                  \
            float v[8] = {ld[ff][0].x, ld[ff][0].y, ld[ff][0].z, ld[ff][0].w,     \
                          ld[ff][1].x, ld[ff][1].y, ld[ff][1].z, ld[ff][1].w};    \
            f16x8 hi, lo;                                                         \
            _Pragma("unroll")                                                     \
            for (int i = 0; i < 8; ++i) {                                         \
                _Float16 h = (_Float16)v[i];                                      \
                hi[i] = h; lo[i] = (_Float16)(v[i] - (float)h);                   \
            }                                                                     \
            *(f16x8*)&xh[((size_t)f * 64 + lane) * 8] = hi;                       \
            *(f16x8*)&xl[((size_t)f * 64 + lane) * 8] = lo;                       \
        }                                                                         \
    }

    // prologue: tile 0
    K1_ISSUE(0)
    K1_STAGE()

    for (int tt = 0; tt < 8; ++tt) {
        __syncthreads();                       // B1: tile tt visible in LDS
        // combine + store scores of tile tt-1
        if (tt > 0 && t < 32) {
            const float* pp = &part[(tt - 1) & 1][0][t];
            float ss = pp[0] + pp[32] + pp[64] + pp[96] + pp[128] + pp[160] + pp[192] + pp[224];
            scores[brow0 + (tt - 1) * 32 + t] = __expf(ss);   // faithful: no max-sub
        }
        // issue next tile's global loads early (hide HBM under compute)
        if (tt < 7) K1_ISSUE(tt + 1)

        // compute tile tt: ds_read + MFMA vs register B
        f32x4 acc0 = {0.f, 0.f, 0.f, 0.f}, acc1 = {0.f, 0.f, 0.f, 0.f};
#pragma unroll
        for (int ks = 0; ks < 8; ++ks) {
            f16x8 ah0 = *(const f16x8*)&xh[((size_t)(ks) * 64 + lane) * 8];
            f16x8 al0 = *(const f16x8*)&xl[((size_t)(ks) * 64 + lane) * 8];
            f16x8 ah1 = *(const f16x8*)&xh[((size_t)(8 + ks) * 64 + lane) * 8];
            f16x8 al1 = *(const f16x8*)&xl[((size_t)(8 + ks) * 64 + lane) * 8];
            acc0 = __builtin_amdgcn_mfma_f32_16x16x32_f16(ah0, Bh[ks], acc0, 0, 0, 0);
            acc0 = __builtin_amdgcn_mfma_f32_16x16x32_f16(ah0, Bl[ks], acc0, 0, 0, 0);
            acc0 = __builtin_amdgcn_mfma_f32_16x16x32_f16(al0, Bh[ks], acc0, 0, 0, 0);
            acc1 = __builtin_amdgcn_mfma_f32_16x16x32_f16(ah1, Bh[ks], acc1, 0, 0, 0);
            acc1 = __builtin_amdgcn_mfma_f32_16x16x32_f16(ah1, Bl[ks], acc1, 0, 0, 0);
            acc1 = __builtin_amdgcn_mfma_f32_16x16x32_f16(al1, Bh[ks], acc1, 0, 0, 0);
        }
        // epilogue: tanh + dot-u partial over this wave's 16 cols, 16-lane reduce
#pragma unroll
        for (int mt = 0; mt < 2; ++mt) {
            f32x4 a = mt ? acc1 : acc0;
#pragma unroll
            for (int r = 0; r < 4; ++r) {
                float s = tanh_fast(a[r] + bb) * uu;
                s += __shfl_xor(s, 8, 64);
                s += __shfl_xor(s, 4, 64);
                s += __shfl_xor(s, 2, 64);
                s += __shfl_xor(s, 1, 64);
                if (lr == 0) part[tt & 1][wv][mt * 16 + lg * 4 + r] = s;
            }
        }
        __syncthreads();                       // B2: all reads of tile tt done
        if (tt < 7) K1_STAGE()                 // write-late: stage tile tt+1
    }
    __syncthreads();
    if (t < 32) {
        const float* pp = &part[1][0][t];
        float ss = pp[0] + pp[32] + pp[64] + pp[96] + pp[128] + pp[160] + pp[192] + pp[224];
        scores[brow0 + 7 * 32 + t] = __expf(ss);
    }
#undef K1_ISSUE
#undef K1_STAGE
}

// ---- K2: out[b,d] = sum_s x[b,s,d]*score[b,s] / (sum_s score + 1e-8) --------
// One block (512 thr = 8 waves) per b; wave w covers s in [w*64, w*64+64):
// 64 independent float4 loads per lane -> deep VMEM queue. LDS combine.
__global__ __launch_bounds__(512) void k_out(
    const float* __restrict__ x, const float* __restrict__ scores,
    float* __restrict__ out)
{
    __shared__ float sc[S_];
    __shared__ float red[8];
    __shared__ float pbuf[8][D_];

    const int t = threadIdx.x, b = blockIdx.x;
    const int lane = t & 63, w = t >> 6;

    float v = scores[(size_t)b * S_ + t];
    sc[t] = v;
    float rv = v;
#pragma unroll
    for (int m = 32; m >= 1; m >>= 1) rv += __shfl_xor(rv, m, 64);
    if (lane == 0) red[w] = rv;
    __syncthreads();

    const float* xp = x + ((size_t)b * S_ + (size_t)w * 64) * D_ + lane * 4;
    f32x4 a0 = {0.f, 0.f, 0.f, 0.f}, a1 = {0.f, 0.f, 0.f, 0.f};
#pragma unroll 8
    for (int j = 0; j < 64; j += 2) {
        float4 xa = *(const float4*)(xp + (size_t)j * D_);
        float4 xb = *(const float4*)(xp + (size_t)(j + 1) * D_);
        float s0 = sc[w * 64 + j], s1 = sc[w * 64 + j + 1];
        a0[0] = fmaf(xa.x, s0, a0[0]); a0[1] = fmaf(xa.y, s0, a0[1]);
        a0[2] = fmaf(xa.z, s0, a0[2]); a0[3] = fmaf(xa.w, s0, a0[3]);
        a1[0] = fmaf(xb.x, s1, a1[0]); a1[1] = fmaf(xb.y, s1, a1[1]);
        a1[2] = fmaf(xb.z, s1, a1[2]); a1[3] = fmaf(xb.w, s1, a1[3]);
    }
    a0[0] += a1[0]; a0[1] += a1[1]; a0[2] += a1[2]; a0[3] += a1[3];
    *(f32x4*)&pbuf[w][lane * 4] = a0;
    __syncthreads();

    if (t < D_) {
        float denom = 0.f;
#pragma unroll
        for (int i = 0; i < 8; ++i) denom += red[i];
        const float inv = 1.0f / (denom + 1e-8f);
        float r = 0.f;
#pragma unroll
        for (int i = 0; i < 8; ++i) r += pbuf[i][t];
        out[b * D_ + t] = r * inv;
    }
}

extern "C" void kernel_launch(void* const* d_in, const int* in_sizes, int n_in,
                              void* d_out, int out_size, void* d_ws, size_t ws_size,
                              hipStream_t stream)
{
    const float* x    = (const float*)d_in[0];
    const float* W    = (const float*)d_in[1];
    const float* bvec = (const float*)d_in[2];
    const float* u    = (const float*)d_in[3];
    float* out = (float*)d_out;
    float* scores = (float*)d_ws;   // BS floats = 512 KB scratch

    k_scores<<<512, 512, 0, stream>>>(x, W, bvec, u, scores);
    k_out   <<<B_, 512, 0, stream>>>(x, scores, out);
}

// Round 6
// 217.404 us; speedup vs baseline: 1.3725x; 1.0325x over previous
//
#include <hip/hip_runtime.h>
#include <math.h>

typedef _Float16 f16x8 __attribute__((ext_vector_type(8)));
typedef float    f32x4 __attribute__((ext_vector_type(4)));

constexpr int B_ = 256, S_ = 512, D_ = 256, A_ = 128;

__device__ __forceinline__ float tanh_fast(float v) {
    // tanh(v) = 1 - 2/(1 + e^{2v}); correct at +-inf. ~2e-6 abs err.
    return 1.0f - 2.0f / (1.0f + __expf(2.0f * v));
}

// ---- Fused: out[b,:] = (sum_s x[b,s,:]*ait[s]) / (sum ait + 1e-8),
//      ait[s] = exp( tanh(x[b,s,:] @ W + bvec) . u )
// One block per b (256 blocks x 512 thr = 8 waves). Phase 1: 16 tiles x 32 rows,
// MFMA 3-term split-f16 (x hi/lo staged frag-major in LDS; W hi/lo in registers,
// wave wv owns att cols [16wv,16wv+16)). Scores stay in LDS. Phase 2: denom
// reduce. Phase 3: weighted sum re-reading x[b] (L1/L2-hot, same CU).
__global__ __launch_bounds__(512, 2) void k_fused(
    const float* __restrict__ x, const float* __restrict__ W,
    const float* __restrict__ bvec, const float* __restrict__ u,
    float* __restrict__ out)
{
    __shared__ _Float16 xh[16 * 64 * 8];   // 16 frags (2 mt x 8 ks) x 64 lanes x 8 = 16 KB
    __shared__ _Float16 xl[16 * 64 * 8];   // 16 KB
    __shared__ float    part[2][8][32];    // 2 KB parity-buffered row partials
    __shared__ float    sc[S_];            // 2 KB scores for this b
    __shared__ float    red[8];
    __shared__ float    pbuf[8][D_];       // 8 KB phase-3 partials

    const int t    = threadIdx.x;
    const int lane = t & 63, wv = t >> 6;        // wv = 0..7 (= nf)
    const int lr   = lane & 15, lg = lane >> 4;
    const int b    = blockIdx.x;
    const float* __restrict__ xb = x + (size_t)b * S_ * D_;

    // --- self-pack B fragments for nf = wv (hi + lo): B[k=ks*32+lg*8+i][n=wv*16+lr]
    f16x8 Bh[8], Bl[8];
#pragma unroll
    for (int ks = 0; ks < 8; ++ks) {
        const float* wp = W + (size_t)(ks * 32 + lg * 8) * A_ + wv * 16 + lr;
#pragma unroll
        for (int i = 0; i < 8; ++i) {
            float v = wp[(size_t)i * A_];
            _Float16 h = (_Float16)v;
            Bh[ks][i] = h;
            Bl[ks][i] = (_Float16)(v - (float)h);
        }
    }
    const float bb = bvec[wv * 16 + lr];
    const float uu = u[wv * 16 + lr];

    // staging regs: wave wv stages frags f = {2wv, 2wv+1}; f=(mt,ks): mt=f>>3, ks=f&7
    float4 ld[2][2];

#define K1_ISSUE(TT)                                                              \
    {                                                                             \
        _Pragma("unroll")                                                         \
        for (int ff = 0; ff < 2; ++ff) {                                          \
            int f = wv * 2 + ff;                                                  \
            const float* p = xb + (size_t)((TT) * 32 + ((f >> 3) << 4) + lr) * D_ \
                                + ((f & 7) << 5) + (lg << 3);                     \
            ld[ff][0] = *(const float4*)p;                                        \
            ld[ff][1] = *(const float4*)(p + 4);                                  \
        }                                                                         \
    }

#define K1_STAGE()                                                                \
    {                                                                             \
        _Pragma("unroll")                                                         \
        for (int ff = 0; ff < 2; ++ff) {                                          \
            int f = wv * 2 + ff;                                                  \
            float v[8] = {ld[ff][0].x, ld[ff][0].y, ld[ff][0].z, ld[ff][0].w,     \
                          ld[ff][1].x, ld[ff][1].y, ld[ff][1].z, ld[ff][1].w};    \
            f16x8 hi, lo;                                                         \
            _Pragma("unroll")                                                     \
            for (int i = 0; i < 8; ++i) {                                         \
                _Float16 h = (_Float16)v[i];                                      \
                hi[i] = h; lo[i] = (_Float16)(v[i] - (float)h);                   \
            }                                                                     \
            *(f16x8*)&xh[((size_t)f * 64 + lane) * 8] = hi;                       \
            *(f16x8*)&xl[((size_t)f * 64 + lane) * 8] = lo;                       \
        }                                                                         \
    }

    // ---- Phase 1: scores for rows 0..511 of this b ----
    K1_ISSUE(0)
    K1_STAGE()

    for (int tt = 0; tt < 16; ++tt) {
        __syncthreads();                       // B1: tile tt visible in LDS
        if (tt > 0 && t < 32) {                // finalize tile tt-1 -> sc[]
            const float* pp = &part[(tt - 1) & 1][0][t];
            float ss = pp[0] + pp[32] + pp[64] + pp[96] + pp[128] + pp[160] + pp[192] + pp[224];
            sc[(tt - 1) * 32 + t] = __expf(ss);   // faithful: no max-sub
        }
        if (tt < 15) K1_ISSUE(tt + 1)          // issue-early (T14)

        f32x4 acc0 = {0.f, 0.f, 0.f, 0.f}, acc1 = {0.f, 0.f, 0.f, 0.f};
#pragma unroll
        for (int ks = 0; ks < 8; ++ks) {
            f16x8 ah0 = *(const f16x8*)&xh[((size_t)(ks) * 64 + lane) * 8];
            f16x8 al0 = *(const f16x8*)&xl[((size_t)(ks) * 64 + lane) * 8];
            f16x8 ah1 = *(const f16x8*)&xh[((size_t)(8 + ks) * 64 + lane) * 8];
            f16x8 al1 = *(const f16x8*)&xl[((size_t)(8 + ks) * 64 + lane) * 8];
            acc0 = __builtin_amdgcn_mfma_f32_16x16x32_f16(ah0, Bh[ks], acc0, 0, 0, 0);
            acc0 = __builtin_amdgcn_mfma_f32_16x16x32_f16(ah0, Bl[ks], acc0, 0, 0, 0);
            acc0 = __builtin_amdgcn_mfma_f32_16x16x32_f16(al0, Bh[ks], acc0, 0, 0, 0);
            acc1 = __builtin_amdgcn_mfma_f32_16x16x32_f16(ah1, Bh[ks], acc1, 0, 0, 0);
            acc1 = __builtin_amdgcn_mfma_f32_16x16x32_f16(ah1, Bl[ks], acc1, 0, 0, 0);
            acc1 = __builtin_amdgcn_mfma_f32_16x16x32_f16(al1, Bh[ks], acc1, 0, 0, 0);
        }
        // epilogue: tanh + dot-u partial over this wave's 16 cols, 16-lane reduce
#pragma unroll
        for (int mt = 0; mt < 2; ++mt) {
            f32x4 a = mt ? acc1 : acc0;
#pragma unroll
            for (int r = 0; r < 4; ++r) {
                float s = tanh_fast(a[r] + bb) * uu;
                s += __shfl_xor(s, 8, 64);
                s += __shfl_xor(s, 4, 64);
                s += __shfl_xor(s, 2, 64);
                s += __shfl_xor(s, 1, 64);
                if (lr == 0) part[tt & 1][wv][mt * 16 + lg * 4 + r] = s;
            }
        }
        __syncthreads();                       // B2: all reads of tile tt done
        if (tt < 15) K1_STAGE()                // write-late: stage tile tt+1
    }
    // finalize tile 15 (parity 15&1 = 1); part writes ordered by B2 above
    if (t < 32) {
        const float* pp = &part[1][0][t];
        float ss = pp[0] + pp[32] + pp[64] + pp[96] + pp[128] + pp[160] + pp[192] + pp[224];
        sc[15 * 32 + t] = __expf(ss);
    }
    __syncthreads();                           // sc[] complete
#undef K1_ISSUE
#undef K1_STAGE

    // ---- Phase 2: denominator ----
    {
        float v = sc[wv * 64 + lane];
#pragma unroll
        for (int m = 32; m >= 1; m >>= 1) v += __shfl_xor(v, m, 64);
        if (lane == 0) red[wv] = v;
    }
    __syncthreads();
    float denom = 0.f;
#pragma unroll
    for (int i = 0; i < 8; ++i) denom += red[i];
    const float inv = 1.0f / (denom + 1e-8f);

    // ---- Phase 3: out[b,d] = sum_s x[b,s,d]*sc[s] * inv  (x L1/L2-hot) ----
    const float* xp = xb + (size_t)(wv * 64) * D_ + lane * 4;
    f32x4 a0 = {0.f, 0.f, 0.f, 0.f}, a1 = {0.f, 0.f, 0.f, 0.f};
#pragma unroll 8
    for (int j = 0; j < 64; j += 2) {
        float4 va = *(const float4*)(xp + (size_t)j * D_);
        float4 vb = *(const float4*)(xp + (size_t)(j + 1) * D_);
        float s0 = sc[wv * 64 + j], s1 = sc[wv * 64 + j + 1];
        a0[0] = fmaf(va.x, s0, a0[0]); a0[1] = fmaf(va.y, s0, a0[1]);
        a0[2] = fmaf(va.z, s0, a0[2]); a0[3] = fmaf(va.w, s0, a0[3]);
        a1[0] = fmaf(vb.x, s1, a1[0]); a1[1] = fmaf(vb.y, s1, a1[1]);
        a1[2] = fmaf(vb.z, s1, a1[2]); a1[3] = fmaf(vb.w, s1, a1[3]);
    }
    a0[0] += a1[0]; a0[1] += a1[1]; a0[2] += a1[2]; a0[3] += a1[3];
    *(f32x4*)&pbuf[wv][lane * 4] = a0;
    __syncthreads();

    if (t < D_) {
        float r = 0.f;
#pragma unroll
        for (int i = 0; i < 8; ++i) r += pbuf[i][t];
        out[b * D_ + t] = r * inv;
    }
}

extern "C" void kernel_launch(void* const* d_in, const int* in_sizes, int n_in,
                              void* d_out, int out_size, void* d_ws, size_t ws_size,
                              hipStream_t stream)
{
    const float* x    = (const float*)d_in[0];
    const float* W    = (const float*)d_in[1];
    const float* bvec = (const float*)d_in[2];
    const float* u    = (const float*)d_in[3];
    float* out = (float*)d_out;

    k_fused<<<B_, 512, 0, stream>>>(x, W, bvec, u, out);
}